// Round 10
// baseline (1273.742 us; speedup 1.0000x reference)
//
#include <hip/hip_runtime.h>
#include <stdint.h>

#define BB 16
#define NN 4096
#define DD 128
#define MM 1024
#define RADIUS2 0.04f
#define TPB 256
#define PPT 16             // points per lane PER GRAPH (proven r3/r5/r8)
#define NPAIR (PPT / 2)
#define NW 4               // 4 waves, 1 per SIMD

typedef unsigned long long u64;
typedef unsigned int u32;
typedef float f32x2 __attribute__((ext_vector_type(2)));
typedef unsigned int uint2v __attribute__((ext_vector_type(2)));

__device__ __forceinline__ u32 umin2(u32 a, u32 b) { return a < b ? a : b; }
__device__ __forceinline__ u32 umin3(u32 a, u32 b, u32 c) { return umin2(umin2(a, b), c); }
__device__ __forceinline__ float fmax3(float a, float b, float c) { return fmaxf(fmaxf(a, b), c); }

template <int CTRL>
__device__ __forceinline__ float dpp_fmax(float v) {
    int o = __builtin_amdgcn_update_dpp(0, __float_as_int(v), CTRL, 0xF, 0xF, true);
    return fmaxf(v, __int_as_float(o));
}
__device__ __forceinline__ float xor16_fmax(float v) {
#if __has_builtin(__builtin_amdgcn_permlane16_swap)
    uint2v r = __builtin_amdgcn_permlane16_swap(__float_as_uint(v), __float_as_uint(v), false, false);
    return fmaxf(__uint_as_float(r[0]), __uint_as_float(r[1]));
#else
    int o = __builtin_amdgcn_ds_swizzle(__float_as_int(v), 0x401F);
    return fmaxf(v, __int_as_float(o));
#endif
}
__device__ __forceinline__ float xor32_fmax(float v) {
#if __has_builtin(__builtin_amdgcn_permlane32_swap)
    uint2v r = __builtin_amdgcn_permlane32_swap(__float_as_uint(v), __float_as_uint(v), false, false);
    return fmaxf(__uint_as_float(r[0]), __uint_as_float(r[1]));
#else
    return fmaxf(v, __shfl_xor(v, 32, 64));
#endif
}
__device__ __forceinline__ float wave_fmax(float v) {
    v = dpp_fmax<0xB1>(v);     // quad_perm xor1
    v = dpp_fmax<0x4E>(v);     // quad_perm xor2
    v = dpp_fmax<0x141>(v);    // row_half_mirror
    v = dpp_fmax<0x140>(v);    // row_mirror
    v = xor16_fmax(v);
    v = xor32_fmax(v);
    return v;
}

// ---------------------------------------------------------------------------
// FPS: 8 blocks x 2 graphs, but BOTH graphs live in the SAME wave's
// instruction stream (ILP, not TLP): each thread owns 16 points of graph A
// and 16 of graph B. The two serial chains are independent, so each fills
// the other's dependency-latency bubbles deterministically. One barrier per
// iteration serves both graphs' cross-wave exchanges (sync tail amortized 2x).
// Per-graph logic byte-identical to the passing r5/r8 kernels.
// Tie-break = lowest global index at every level = jnp.argmax semantics.
// ---------------------------------------------------------------------------
__global__ __launch_bounds__(TPB) void fps_kernel(const float* __restrict__ pos,
                                                  int* __restrict__ idx_out) {
    const int tid  = threadIdx.x;
    const int wid  = tid >> 6;
    const int lane = tid & 63;
    const int gA   = blockIdx.x * 2;
    const int gB   = gA + 1;

    __shared__ float4 posA[NN], posB[NN];          // 128 KB, xyz_ padded
    __shared__ float4 fpart[2][2][NW];             // [graph][buf][wave] {wmax,x,y,z}
    __shared__ u32    ipart[2][2][NW];
    __shared__ int    trace[2][MM];                // 8 KB

    const float* pga = pos + (size_t)gA * NN * 3;
    const float* pgb = pos + (size_t)gB * NN * 3;
    for (int k = tid; k < NN * 3; k += TPB) {
        ((float*)&posA[k / 3])[k % 3] = pga[k];
        ((float*)&posB[k / 3])[k % 3] = pgb[k];
    }
    if (tid == 0) { trace[0][0] = 0; trace[1][0] = 0; }   // idx[0]=0
    __syncthreads();

    const int base = tid * PPT;
    f32x2 pxA[NPAIR], pyA[NPAIR], pzA[NPAIR], dA[NPAIR];
    f32x2 pxB[NPAIR], pyB[NPAIR], pzB[NPAIR], dB[NPAIR];
#pragma unroll
    for (int j = 0; j < NPAIR; ++j) {
        float4 a0 = posA[base + 2 * j], a1 = posA[base + 2 * j + 1];
        pxA[j] = (f32x2){a0.x, a1.x}; pyA[j] = (f32x2){a0.y, a1.y}; pzA[j] = (f32x2){a0.z, a1.z};
        dA[j] = (f32x2){__builtin_inff(), __builtin_inff()};
        float4 b0 = posB[base + 2 * j], b1 = posB[base + 2 * j + 1];
        pxB[j] = (f32x2){b0.x, b1.x}; pyB[j] = (f32x2){b0.y, b1.y}; pzB[j] = (f32x2){b0.z, b1.z};
        dB[j] = (f32x2){__builtin_inff(), __builtin_inff()};
    }

    float4 lpA = posA[0], lpB = posB[0];
    float lxa = lpA.x, lya = lpA.y, lza = lpA.z;
    float lxb = lpB.x, lyb = lpB.y, lzb = lpB.z;

    for (int m = 1; m < MM; ++m) {
        // ---- dist updates, A and B interleaved (independent chains = ILP)
        {
#pragma clang fp contract(off)
            f32x2 vxa = {lxa, lxa}, vya = {lya, lya}, vza = {lza, lza};
            f32x2 vxb = {lxb, lxb}, vyb = {lyb, lyb}, vzb = {lzb, lzb};
#pragma unroll
            for (int j = 0; j < NPAIR; ++j) {
                f32x2 dxa = pxA[j] - vxa, dya = pyA[j] - vya, dza = pzA[j] - vza;
                f32x2 dxb = pxB[j] - vxb, dyb = pyB[j] - vyb, dzb = pzB[j] - vzb;
                f32x2 da = dxa * dxa + dya * dya; da = da + dza * dza;
                f32x2 db = dxb * dxb + dyb * dyb; db = db + dzb * dzb;
                dA[j] = __builtin_elementwise_min(dA[j], da);
                dB[j] = __builtin_elementwise_min(dB[j], db);
            }
        }

        // ---- lane max trees (independent)
        float ta0 = fmaxf(dA[0].x, dA[0].y), ta1 = fmaxf(dA[1].x, dA[1].y);
        float ta2 = fmaxf(dA[2].x, dA[2].y), ta3 = fmaxf(dA[3].x, dA[3].y);
        float ta4 = fmaxf(dA[4].x, dA[4].y), ta5 = fmaxf(dA[5].x, dA[5].y);
        float ta6 = fmaxf(dA[6].x, dA[6].y), ta7 = fmaxf(dA[7].x, dA[7].y);
        float tmaxA = fmax3(fmax3(ta0, ta1, ta2), fmax3(ta3, ta4, ta5), fmaxf(ta6, ta7));
        float tb0 = fmaxf(dB[0].x, dB[0].y), tb1 = fmaxf(dB[1].x, dB[1].y);
        float tb2 = fmaxf(dB[2].x, dB[2].y), tb3 = fmaxf(dB[3].x, dB[3].y);
        float tb4 = fmaxf(dB[4].x, dB[4].y), tb5 = fmaxf(dB[5].x, dB[5].y);
        float tb6 = fmaxf(dB[6].x, dB[6].y), tb7 = fmaxf(dB[7].x, dB[7].y);
        float tmaxB = fmax3(fmax3(tb0, tb1, tb2), fmax3(tb3, tb4, tb5), fmaxf(tb6, tb7));

        // ---- local scans vs own tmax (lowest k), sentinel 64
        u32 cA[PPT], cB[PPT];
#pragma unroll
        for (int j = 0; j < NPAIR; ++j) {
            cA[2 * j]     = (dA[j].x == tmaxA) ? (u32)(2 * j)     : 64u;
            cA[2 * j + 1] = (dA[j].y == tmaxA) ? (u32)(2 * j + 1) : 64u;
            cB[2 * j]     = (dB[j].x == tmaxB) ? (u32)(2 * j)     : 64u;
            cB[2 * j + 1] = (dB[j].y == tmaxB) ? (u32)(2 * j + 1) : 64u;
        }
        u32 sA = umin3(umin3(umin3(cA[0], cA[1], cA[2]),  umin3(cA[3], cA[4], cA[5]),
                             umin3(cA[6], cA[7], cA[8])),
                       umin2(umin3(cA[9], cA[10], cA[11]), umin3(cA[12], cA[13], cA[14])),
                       cA[15]);
        u32 sB = umin3(umin3(umin3(cB[0], cB[1], cB[2]),  umin3(cB[3], cB[4], cB[5]),
                             umin3(cB[6], cB[7], cB[8])),
                       umin2(umin3(cB[9], cB[10], cB[11]), umin3(cB[12], cB[13], cB[14])),
                       cB[15]);
        u32 gidxA = (u32)base + sA;
        u32 gidxB = (u32)base + sB;

        float4 spA = posA[gidxA];          // speculative winner coords (overlapped)
        float4 spB = posB[gidxB];

        // ---- wave reduces: two independent DPP chains interleave
        float wmaxA = wave_fmax(tmaxA);
        float wmaxB = wave_fmax(tmaxB);

        u64 mkA = __ballot(tmaxA == wmaxA);
        u64 mkB = __ballot(tmaxB == wmaxB);
        int ownerA = (int)__builtin_ctzll(mkA);
        int ownerB = (int)__builtin_ctzll(mkB);

        const int buf = m & 1;
        if (lane == ownerA) {
            fpart[0][buf][wid] = make_float4(wmaxA, spA.x, spA.y, spA.z);
            ipart[0][buf][wid] = gidxA;
        }
        if (lane == ownerB) {
            fpart[1][buf][wid] = make_float4(wmaxB, spB.x, spB.y, spB.z);
            ipart[1][buf][wid] = gidxB;
        }
        __syncthreads();                   // one barrier serves BOTH graphs

        // ---- folds (independent)
        {
            float4 q0 = fpart[0][buf][0], q1 = fpart[0][buf][1];
            float4 q2 = fpart[0][buf][2], q3 = fpart[0][buf][3];
            float g = fmaxf(fmaxf(q0.x, q1.x), fmaxf(q2.x, q3.x));
            float nx = q3.y, ny = q3.z, nz = q3.w;
            bool s2 = (q2.x == g); nx = s2 ? q2.y : nx; ny = s2 ? q2.z : ny; nz = s2 ? q2.w : nz;
            bool s1 = (q1.x == g); nx = s1 ? q1.y : nx; ny = s1 ? q1.z : ny; nz = s1 ? q1.w : nz;
            bool s0 = (q0.x == g); nx = s0 ? q0.y : nx; ny = s0 ? q0.z : ny; nz = s0 ? q0.w : nz;
            lxa = nx; lya = ny; lza = nz;
            if (tid == 0) {
                u32 li = ipart[0][buf][3];
                li = s2 ? ipart[0][buf][2] : li;
                li = s1 ? ipart[0][buf][1] : li;
                li = s0 ? ipart[0][buf][0] : li;
                trace[0][m] = (int)li;
            }
        }
        {
            float4 q0 = fpart[1][buf][0], q1 = fpart[1][buf][1];
            float4 q2 = fpart[1][buf][2], q3 = fpart[1][buf][3];
            float g = fmaxf(fmaxf(q0.x, q1.x), fmaxf(q2.x, q3.x));
            float nx = q3.y, ny = q3.z, nz = q3.w;
            bool s2 = (q2.x == g); nx = s2 ? q2.y : nx; ny = s2 ? q2.z : ny; nz = s2 ? q2.w : nz;
            bool s1 = (q1.x == g); nx = s1 ? q1.y : nx; ny = s1 ? q1.z : ny; nz = s1 ? q1.w : nz;
            bool s0 = (q0.x == g); nx = s0 ? q0.y : nx; ny = s0 ? q0.z : ny; nz = s0 ? q0.w : nz;
            lxb = nx; lyb = ny; lzb = nz;
            if (tid == 0) {
                u32 li = ipart[1][buf][3];
                li = s2 ? ipart[1][buf][2] : li;
                li = s1 ? ipart[1][buf][1] : li;
                li = s0 ? ipart[1][buf][0] : li;
                trace[1][m] = (int)li;
            }
        }
    }

    __syncthreads();                       // trace visibility for the dump
    for (int k = tid; k < MM; k += TPB) {
        idx_out[gA * MM + k] = trace[0][k];
        idx_out[gB * MM + k] = trace[1][k];
    }
}

// ---------------------------------------------------------------------------
// Phase 2a: gather sampled_x (float4-vectorized).
// ---------------------------------------------------------------------------
__global__ void gather_x_kernel(const float* __restrict__ x,
                                const int* __restrict__ idx,
                                float* __restrict__ out) {
    int t = blockIdx.x * blockDim.x + threadIdx.x;
    if (t >= BB * MM * DD / 4) return;
    int row = t >> 5;               // DD/4 = 32 float4 per row
    int c4  = (t & 31) << 2;
    int b   = row >> 10;
    int n   = idx[row];
    const float4 v = *(const float4*)(x + ((size_t)(b * NN + n) * DD + c4));
    *(float4*)(out + (size_t)row * DD + c4) = v;
}

// ---------------------------------------------------------------------------
// Phase 2b: gather sampled_pos + batch ids (as float).
// ---------------------------------------------------------------------------
__global__ void gather_pb_kernel(const float* __restrict__ pos,
                                 const int* __restrict__ idx,
                                 float* __restrict__ spos,
                                 float* __restrict__ sbatch) {
    int r = blockIdx.x * blockDim.x + threadIdx.x;
    if (r >= BB * MM) return;
    int b = r >> 10;
    int n = idx[r];
    const float* p = pos + (size_t)(b * NN + n) * 3;
    spos[r * 3 + 0] = p[0];
    spos[r * 3 + 1] = p[1];
    spos[r * 3 + 2] = p[2];
    sbatch[r] = (float)b;
}

// ---------------------------------------------------------------------------
// Phase 3: radius adjacency, bit-exact d2 (no FMA).
// ---------------------------------------------------------------------------
__global__ void adj_kernel(const float* __restrict__ spos,
                           float* __restrict__ adj) {
    int row = blockIdx.x;           // b*MM + i
    int b   = row >> 10;
    int i   = row & (MM - 1);
    const float* pb = spos + (size_t)b * MM * 3;
    float xi = pb[i * 3 + 0];
    float yi = pb[i * 3 + 1];
    float zi = pb[i * 3 + 2];

    int j0 = threadIdx.x << 2;
    float4 r;
    float* o = adj + (size_t)row * MM;
#pragma unroll
    for (int k = 0; k < 4; ++k) {
        int j = j0 + k;
        float dx = xi - pb[j * 3 + 0];
        float dy = yi - pb[j * 3 + 1];
        float dz = zi - pb[j * 3 + 2];
        float d2 = __fadd_rn(__fadd_rn(__fmul_rn(dx, dx), __fmul_rn(dy, dy)),
                             __fmul_rn(dz, dz));
        float v = (d2 <= RADIUS2 && j != i) ? 1.0f : 0.0f;
        ((float*)&r)[k] = v;
    }
    *(float4*)(o + j0) = r;
}

// ---------------------------------------------------------------------------
extern "C" void kernel_launch(void* const* d_in, const int* in_sizes, int n_in,
                              void* d_out, int out_size, void* d_ws, size_t ws_size,
                              hipStream_t stream) {
    const float* x   = (const float*)d_in[0];
    const float* pos = (const float*)d_in[1];

    float* out    = (float*)d_out;
    int*   idx_ws = (int*)d_ws;                 // BB*MM ints = 64 KB scratch

    float* sx   = out;                          // [BB*MM, DD]
    float* spos = sx + (size_t)BB * MM * DD;    // [BB*MM, 3]
    float* sbat = spos + (size_t)BB * MM * 3;   // [BB*MM]
    float* adj  = sbat + (size_t)BB * MM;       // [BB, MM, MM]

    fps_kernel<<<BB / 2, TPB, 0, stream>>>(pos, idx_ws);
    gather_x_kernel<<<(BB * MM * DD / 4 + 255) / 256, 256, 0, stream>>>(x, idx_ws, sx);
    gather_pb_kernel<<<(BB * MM + 255) / 256, 256, 0, stream>>>(pos, idx_ws, spos, sbat);
    adj_kernel<<<BB * MM, 256, 0, stream>>>(spos, adj);
}

// Round 11
// 1248.961 us; speedup vs baseline: 1.0198x; 1.0198x over previous
//
#include <hip/hip_runtime.h>
#include <stdint.h>

#define BB 16
#define NN 4096
#define DD 128
#define MM 1024
#define RADIUS2 0.04f
#define TPB 256
#define PPT 16             // points per lane PER GRAPH
#define NPAIR (PPT / 2)
#define NW 4               // 4 waves, 1 per SIMD

typedef unsigned long long u64;
typedef unsigned int u32;
typedef float f32x2 __attribute__((ext_vector_type(2)));
typedef unsigned int uint2v __attribute__((ext_vector_type(2)));

__device__ __forceinline__ u32 umin2(u32 a, u32 b) { return a < b ? a : b; }
__device__ __forceinline__ u32 umin3(u32 a, u32 b, u32 c) { return umin2(umin2(a, b), c); }
__device__ __forceinline__ float fmax3(float a, float b, float c) { return fmaxf(fmaxf(a, b), c); }

template <int CTRL>
__device__ __forceinline__ float dpp_fmax(float v) {
    int o = __builtin_amdgcn_update_dpp(0, __float_as_int(v), CTRL, 0xF, 0xF, true);
    return fmaxf(v, __int_as_float(o));
}
__device__ __forceinline__ float xor16_fmax(float v) {
#if __has_builtin(__builtin_amdgcn_permlane16_swap)
    uint2v r = __builtin_amdgcn_permlane16_swap(__float_as_uint(v), __float_as_uint(v), false, false);
    return fmaxf(__uint_as_float(r[0]), __uint_as_float(r[1]));
#else
    int o = __builtin_amdgcn_ds_swizzle(__float_as_int(v), 0x401F);
    return fmaxf(v, __int_as_float(o));
#endif
}
__device__ __forceinline__ float xor32_fmax(float v) {
#if __has_builtin(__builtin_amdgcn_permlane32_swap)
    uint2v r = __builtin_amdgcn_permlane32_swap(__float_as_uint(v), __float_as_uint(v), false, false);
    return fmaxf(__uint_as_float(r[0]), __uint_as_float(r[1]));
#else
    return fmaxf(v, __shfl_xor(v, 32, 64));
#endif
}
__device__ __forceinline__ float wave_fmax(float v) {
    v = dpp_fmax<0xB1>(v);     // quad_perm xor1
    v = dpp_fmax<0x4E>(v);     // quad_perm xor2
    v = dpp_fmax<0x141>(v);    // row_half_mirror
    v = dpp_fmax<0x140>(v);    // row_mirror
    v = xor16_fmax(v);
    v = xor32_fmax(v);
    return v;
}

// ---------------------------------------------------------------------------
// FPS: 8 blocks x 2 graphs IN THE SAME WAVE'S instruction stream (ILP).
// r10 showed the concept but the allocator capped VGPRs at 132 and
// rematerialized coords from LDS each iter (conflicts 63K->480K). This round:
//   - amdgpu_waves_per_eu(1,1): full 512-VGPR budget (1 wave/SIMD anyway)
//   - volatile staging reads: remat from LDS becomes illegal -> coords MUST
//     stay in registers
//   - running-min scan accumulators: shorter live ranges
// Per-graph logic identical to the passing r5/r8/r10 kernels.
// ---------------------------------------------------------------------------
__global__ __launch_bounds__(TPB)
__attribute__((amdgpu_waves_per_eu(1, 1)))
void fps_kernel(const float* __restrict__ pos, int* __restrict__ idx_out) {
    const int tid  = threadIdx.x;
    const int wid  = tid >> 6;
    const int lane = tid & 63;
    const int gA   = blockIdx.x * 2;
    const int gB   = gA + 1;

    __shared__ float4 posA[NN], posB[NN];          // 128 KB, xyz_ padded
    __shared__ float4 fpart[2][2][NW];             // [graph][buf][wave] {wmax,x,y,z}
    __shared__ u32    ipart[2][2][NW];
    __shared__ int    trace[2][MM];                // 8 KB

    const float* pga = pos + (size_t)gA * NN * 3;
    const float* pgb = pos + (size_t)gB * NN * 3;
    for (int k = tid; k < NN * 3; k += TPB) {
        ((float*)&posA[k / 3])[k % 3] = pga[k];
        ((float*)&posB[k / 3])[k % 3] = pgb[k];
    }
    if (tid == 0) { trace[0][0] = 0; trace[1][0] = 0; }   // idx[0]=0
    __syncthreads();

    const int base = tid * PPT;
    // volatile one-time reads: compiler cannot re-issue them later, so the
    // coordinate arrays are forced to stay register-resident.
    const volatile float* vA = (const volatile float*)&posA[0];
    const volatile float* vB = (const volatile float*)&posB[0];
    f32x2 pxA[NPAIR], pyA[NPAIR], pzA[NPAIR], dA[NPAIR];
    f32x2 pxB[NPAIR], pyB[NPAIR], pzB[NPAIR], dB[NPAIR];
#pragma unroll
    for (int j = 0; j < NPAIR; ++j) {
        int o0 = (base + 2 * j) * 4, o1 = (base + 2 * j + 1) * 4;
        pxA[j] = (f32x2){vA[o0 + 0], vA[o1 + 0]};
        pyA[j] = (f32x2){vA[o0 + 1], vA[o1 + 1]};
        pzA[j] = (f32x2){vA[o0 + 2], vA[o1 + 2]};
        pxB[j] = (f32x2){vB[o0 + 0], vB[o1 + 0]};
        pyB[j] = (f32x2){vB[o0 + 1], vB[o1 + 1]};
        pzB[j] = (f32x2){vB[o0 + 2], vB[o1 + 2]};
        dA[j] = (f32x2){__builtin_inff(), __builtin_inff()};
        dB[j] = (f32x2){__builtin_inff(), __builtin_inff()};
    }

    float4 lpA = posA[0], lpB = posB[0];
    float lxa = lpA.x, lya = lpA.y, lza = lpA.z;
    float lxb = lpB.x, lyb = lpB.y, lzb = lpB.z;

    for (int m = 1; m < MM; ++m) {
        // ---- dist updates, A and B interleaved (independent chains = ILP)
        {
#pragma clang fp contract(off)
            f32x2 vxa = {lxa, lxa}, vya = {lya, lya}, vza = {lza, lza};
            f32x2 vxb = {lxb, lxb}, vyb = {lyb, lyb}, vzb = {lzb, lzb};
#pragma unroll
            for (int j = 0; j < NPAIR; ++j) {
                f32x2 dxa = pxA[j] - vxa, dya = pyA[j] - vya, dza = pzA[j] - vza;
                f32x2 dxb = pxB[j] - vxb, dyb = pyB[j] - vyb, dzb = pzB[j] - vzb;
                f32x2 da = dxa * dxa + dya * dya; da = da + dza * dza;
                f32x2 db = dxb * dxb + dyb * dyb; db = db + dzb * dzb;
                dA[j] = __builtin_elementwise_min(dA[j], da);
                dB[j] = __builtin_elementwise_min(dB[j], db);
            }
        }

        // ---- lane max trees
        float ta0 = fmaxf(dA[0].x, dA[0].y), ta1 = fmaxf(dA[1].x, dA[1].y);
        float ta2 = fmaxf(dA[2].x, dA[2].y), ta3 = fmaxf(dA[3].x, dA[3].y);
        float ta4 = fmaxf(dA[4].x, dA[4].y), ta5 = fmaxf(dA[5].x, dA[5].y);
        float ta6 = fmaxf(dA[6].x, dA[6].y), ta7 = fmaxf(dA[7].x, dA[7].y);
        float tmaxA = fmax3(fmax3(ta0, ta1, ta2), fmax3(ta3, ta4, ta5), fmaxf(ta6, ta7));
        float tb0 = fmaxf(dB[0].x, dB[0].y), tb1 = fmaxf(dB[1].x, dB[1].y);
        float tb2 = fmaxf(dB[2].x, dB[2].y), tb3 = fmaxf(dB[3].x, dB[3].y);
        float tb4 = fmaxf(dB[4].x, dB[4].y), tb5 = fmaxf(dB[5].x, dB[5].y);
        float tb6 = fmaxf(dB[6].x, dB[6].y), tb7 = fmaxf(dB[7].x, dB[7].y);
        float tmaxB = fmax3(fmax3(tb0, tb1, tb2), fmax3(tb3, tb4, tb5), fmaxf(tb6, tb7));

        // ---- local scans (running-min accumulators: short live ranges)
        u32 sA = 64u, sB = 64u;
#pragma unroll
        for (int j = 0; j < NPAIR; ++j) {
            sA = umin3(sA, (dA[j].x == tmaxA) ? (u32)(2 * j)     : 64u,
                           (dA[j].y == tmaxA) ? (u32)(2 * j + 1) : 64u);
            sB = umin3(sB, (dB[j].x == tmaxB) ? (u32)(2 * j)     : 64u,
                           (dB[j].y == tmaxB) ? (u32)(2 * j + 1) : 64u);
        }
        u32 gidxA = (u32)base + sA;
        u32 gidxB = (u32)base + sB;

        float4 spA = posA[gidxA];          // speculative winner coords (overlapped)
        float4 spB = posB[gidxB];

        // ---- wave reduces: two independent DPP chains interleave
        float wmaxA = wave_fmax(tmaxA);
        float wmaxB = wave_fmax(tmaxB);

        u64 mkA = __ballot(tmaxA == wmaxA);
        u64 mkB = __ballot(tmaxB == wmaxB);
        int ownerA = (int)__builtin_ctzll(mkA);
        int ownerB = (int)__builtin_ctzll(mkB);

        const int buf = m & 1;
        if (lane == ownerA) {
            fpart[0][buf][wid] = make_float4(wmaxA, spA.x, spA.y, spA.z);
            ipart[0][buf][wid] = gidxA;
        }
        if (lane == ownerB) {
            fpart[1][buf][wid] = make_float4(wmaxB, spB.x, spB.y, spB.z);
            ipart[1][buf][wid] = gidxB;
        }
        __syncthreads();                   // one barrier serves BOTH graphs

        // ---- folds (independent)
        {
            float4 q0 = fpart[0][buf][0], q1 = fpart[0][buf][1];
            float4 q2 = fpart[0][buf][2], q3 = fpart[0][buf][3];
            float g = fmaxf(fmaxf(q0.x, q1.x), fmaxf(q2.x, q3.x));
            float nx = q3.y, ny = q3.z, nz = q3.w;
            bool s2 = (q2.x == g); nx = s2 ? q2.y : nx; ny = s2 ? q2.z : ny; nz = s2 ? q2.w : nz;
            bool s1 = (q1.x == g); nx = s1 ? q1.y : nx; ny = s1 ? q1.z : ny; nz = s1 ? q1.w : nz;
            bool s0 = (q0.x == g); nx = s0 ? q0.y : nx; ny = s0 ? q0.z : ny; nz = s0 ? q0.w : nz;
            lxa = nx; lya = ny; lza = nz;
            if (tid == 0) {
                u32 li = ipart[0][buf][3];
                li = s2 ? ipart[0][buf][2] : li;
                li = s1 ? ipart[0][buf][1] : li;
                li = s0 ? ipart[0][buf][0] : li;
                trace[0][m] = (int)li;
            }
        }
        {
            float4 q0 = fpart[1][buf][0], q1 = fpart[1][buf][1];
            float4 q2 = fpart[1][buf][2], q3 = fpart[1][buf][3];
            float g = fmaxf(fmaxf(q0.x, q1.x), fmaxf(q2.x, q3.x));
            float nx = q3.y, ny = q3.z, nz = q3.w;
            bool s2 = (q2.x == g); nx = s2 ? q2.y : nx; ny = s2 ? q2.z : ny; nz = s2 ? q2.w : nz;
            bool s1 = (q1.x == g); nx = s1 ? q1.y : nx; ny = s1 ? q1.z : ny; nz = s1 ? q1.w : nz;
            bool s0 = (q0.x == g); nx = s0 ? q0.y : nx; ny = s0 ? q0.z : ny; nz = s0 ? q0.w : nz;
            lxb = nx; lyb = ny; lzb = nz;
            if (tid == 0) {
                u32 li = ipart[1][buf][3];
                li = s2 ? ipart[1][buf][2] : li;
                li = s1 ? ipart[1][buf][1] : li;
                li = s0 ? ipart[1][buf][0] : li;
                trace[1][m] = (int)li;
            }
        }
    }

    __syncthreads();                       // trace visibility for the dump
    for (int k = tid; k < MM; k += TPB) {
        idx_out[gA * MM + k] = trace[0][k];
        idx_out[gB * MM + k] = trace[1][k];
    }
}

// ---------------------------------------------------------------------------
// Phase 2a: gather sampled_x (float4-vectorized).
// ---------------------------------------------------------------------------
__global__ void gather_x_kernel(const float* __restrict__ x,
                                const int* __restrict__ idx,
                                float* __restrict__ out) {
    int t = blockIdx.x * blockDim.x + threadIdx.x;
    if (t >= BB * MM * DD / 4) return;
    int row = t >> 5;               // DD/4 = 32 float4 per row
    int c4  = (t & 31) << 2;
    int b   = row >> 10;
    int n   = idx[row];
    const float4 v = *(const float4*)(x + ((size_t)(b * NN + n) * DD + c4));
    *(float4*)(out + (size_t)row * DD + c4) = v;
}

// ---------------------------------------------------------------------------
// Phase 2b: gather sampled_pos + batch ids (as float).
// ---------------------------------------------------------------------------
__global__ void gather_pb_kernel(const float* __restrict__ pos,
                                 const int* __restrict__ idx,
                                 float* __restrict__ spos,
                                 float* __restrict__ sbatch) {
    int r = blockIdx.x * blockDim.x + threadIdx.x;
    if (r >= BB * MM) return;
    int b = r >> 10;
    int n = idx[r];
    const float* p = pos + (size_t)(b * NN + n) * 3;
    spos[r * 3 + 0] = p[0];
    spos[r * 3 + 1] = p[1];
    spos[r * 3 + 2] = p[2];
    sbatch[r] = (float)b;
}

// ---------------------------------------------------------------------------
// Phase 3: radius adjacency, bit-exact d2 (no FMA).
// ---------------------------------------------------------------------------
__global__ void adj_kernel(const float* __restrict__ spos,
                           float* __restrict__ adj) {
    int row = blockIdx.x;           // b*MM + i
    int b   = row >> 10;
    int i   = row & (MM - 1);
    const float* pb = spos + (size_t)b * MM * 3;
    float xi = pb[i * 3 + 0];
    float yi = pb[i * 3 + 1];
    float zi = pb[i * 3 + 2];

    int j0 = threadIdx.x << 2;
    float4 r;
    float* o = adj + (size_t)row * MM;
#pragma unroll
    for (int k = 0; k < 4; ++k) {
        int j = j0 + k;
        float dx = xi - pb[j * 3 + 0];
        float dy = yi - pb[j * 3 + 1];
        float dz = zi - pb[j * 3 + 2];
        float d2 = __fadd_rn(__fadd_rn(__fmul_rn(dx, dx), __fmul_rn(dy, dy)),
                             __fmul_rn(dz, dz));
        float v = (d2 <= RADIUS2 && j != i) ? 1.0f : 0.0f;
        ((float*)&r)[k] = v;
    }
    *(float4*)(o + j0) = r;
}

// ---------------------------------------------------------------------------
extern "C" void kernel_launch(void* const* d_in, const int* in_sizes, int n_in,
                              void* d_out, int out_size, void* d_ws, size_t ws_size,
                              hipStream_t stream) {
    const float* x   = (const float*)d_in[0];
    const float* pos = (const float*)d_in[1];

    float* out    = (float*)d_out;
    int*   idx_ws = (int*)d_ws;                 // BB*MM ints = 64 KB scratch

    float* sx   = out;                          // [BB*MM, DD]
    float* spos = sx + (size_t)BB * MM * DD;    // [BB*MM, 3]
    float* sbat = spos + (size_t)BB * MM * 3;   // [BB*MM]
    float* adj  = sbat + (size_t)BB * MM;       // [BB, MM, MM]

    fps_kernel<<<BB / 2, TPB, 0, stream>>>(pos, idx_ws);
    gather_x_kernel<<<(BB * MM * DD / 4 + 255) / 256, 256, 0, stream>>>(x, idx_ws, sx);
    gather_pb_kernel<<<(BB * MM + 255) / 256, 256, 0, stream>>>(pos, idx_ws, spos, sbat);
    adj_kernel<<<BB * MM, 256, 0, stream>>>(spos, adj);
}